// Round 2
// baseline (269.512 us; speedup 1.0000x reference)
//
#include <hip/hip_runtime.h>

// WaveletLayer fused v2b: latency-oriented restructure.
//  - s1 reads x*diag_b from global into registers (no a0 LDS staging).
//  - c is materialized once in LDS (a3|d3|d2|gap2|d1); cp is NEVER materialized:
//    r-stages gather C[perm[i]]*g[i] on the fly (perm/diag_g are L1/L2-hot,
//    row-invariant). cp[2563:] is dead in the inverse and never touched.
//  - r2+r3 fused in registers (thread u computes r2[4u..4u+4] + both out quads).
//  - 4 barriers total (was 7). LDS = 28.8 KB -> 4 blocks/CU (32-wave cap).
//
// c physical layout in Cc: a3[0:514) d3[514:1028) d2[1028:2054) gap[2054:2056)
//                          d1 at 2056+[0:2049)   (gap keeps d1 16B-aligned;
//                          gather translation: j >= 2054 ? j+2 : j)
// rawA: A1 = a1[-2..2052) at rawA+4 (r1[0:1026) reuses this region later),
//       A2 = a2[-2..1028) at rawA+2060.

#define NT 512

__global__ __launch_bounds__(NT, 8) void wavelet_fused(
    const float* __restrict__ x,
    const float* __restrict__ diag_b,
    const float* __restrict__ diag_g,
    const float* __restrict__ diag_s,
    const float* __restrict__ dec_lo,
    const float* __restrict__ dec_hi,
    const float* __restrict__ rec_lo,
    const float* __restrict__ rec_hi,
    const int*   __restrict__ perm_idx,
    float* __restrict__ out)
{
    __shared__ __align__(16) float rawA[3088];
    __shared__ __align__(16) float rawC[4112];
    float* const A1 = rawA + 4;     // a1[i], i in [-2, 2052)
    float* const A2 = rawA + 2060;  // a2[i], i in [-2, 1028)
    float* const R1 = rawA + 4;     // r1[0:1026) (a1 dead by then)
    float* const Cc = rawC;

    const int tid = threadIdx.x;
    const long row = blockIdx.x;

    const float lo0=dec_lo[0], lo1=dec_lo[1], lo2=dec_lo[2], lo3=dec_lo[3];
    const float hi0=dec_hi[0], hi1=dec_hi[1], hi2=dec_hi[2], hi3=dec_hi[3];
    const float rl0=rec_lo[0], rl1=rec_lo[1], rl2=rec_lo[2], rl3=rec_lo[3];
    const float rh0=rec_hi[0], rh1=rec_hi[1], rh2=rec_hi[2], rh3=rec_hi[3];

    // zero pads (a1[-2:0), a1[2049:2052), a2[-2:0), a2[1026:1028))
    if (tid < 2) rawA[2 + tid]    = 0.0f;
    if (tid < 3) rawA[2053 + tid] = 0.0f;
    if (tid < 2) rawA[2058 + tid] = 0.0f;
    if (tid < 2) rawA[3086 + tid] = 0.0f;

    // ---- s1: global regs -> a1 (A1), d1 (Cc d1 region) ----
    {
        const float* xr = x + row * 4096;
        float4 xv0 = *(const float4*)(xr + 8*tid);
        float4 xv1 = *(const float4*)(xr + 8*tid + 4);
        float4 bv0 = *(const float4*)(diag_b + 8*tid);
        float4 bv1 = *(const float4*)(diag_b + 8*tid + 4);
        float vm2 = 0.0f, vm1 = 0.0f;
        if (tid > 0) {
            float2 xm = *(const float2*)(xr + 8*tid - 2);
            float2 bm = *(const float2*)(diag_b + 8*tid - 2);
            vm2 = xm.x * bm.x; vm1 = xm.y * bm.y;
        }
        float v0 = xv0.x*bv0.x, v1 = xv0.y*bv0.y, v2 = xv0.z*bv0.z, v3 = xv0.w*bv0.w;
        float v4 = xv1.x*bv1.x, v5 = xv1.y*bv1.y, v6 = xv1.z*bv1.z, v7 = xv1.w*bv1.w;
        float4 av, dv;
        av.x = lo0*v1 + lo1*v0 + lo2*vm1 + lo3*vm2;
        dv.x = hi0*v1 + hi1*v0 + hi2*vm1 + hi3*vm2;
        av.y = lo0*v3 + lo1*v2 + lo2*v1 + lo3*v0;
        dv.y = hi0*v3 + hi1*v2 + hi2*v1 + hi3*v0;
        av.z = lo0*v5 + lo1*v4 + lo2*v3 + lo3*v2;
        dv.z = hi0*v5 + hi1*v4 + hi2*v3 + hi3*v2;
        av.w = lo0*v7 + lo1*v6 + lo2*v5 + lo3*v4;
        dv.w = hi0*v7 + hi1*v6 + hi2*v5 + hi3*v4;
        *(float4*)(A1 + 4*tid) = av;
        *(float4*)(Cc + 2056 + 4*tid) = dv;
        if (tid == 0) {
            // n = 2048 tail: x'[4096],x'[4097] = 0
            float xa = xr[4094]*diag_b[4094], xb = xr[4095]*diag_b[4095];
            A1[2048]        = lo2*xb + lo3*xa;
            Cc[2056 + 2048] = hi2*xb + hi3*xa;
        }
    }
    __syncthreads();

    // ---- s2: a1 -> a2 (A2), d2 -> Cc[1028+..] ----
    for (int p = tid; p < 513; p += NT) {
        float2 u0 = *(const float2*)(A1 + 4*p - 2);
        float4 u1 = *(const float4*)(A1 + 4*p);
        float2 ap, dp;
        ap.x = lo0*u1.y + lo1*u1.x + lo2*u0.y + lo3*u0.x;
        dp.x = hi0*u1.y + hi1*u1.x + hi2*u0.y + hi3*u0.x;
        ap.y = lo0*u1.w + lo1*u1.z + lo2*u1.y + lo3*u1.x;
        dp.y = hi0*u1.w + hi1*u1.z + hi2*u1.y + hi3*u1.x;
        *(float2*)(A2 + 2*p)        = ap;
        *(float2*)(Cc + 1028 + 2*p) = dp;
    }
    __syncthreads();

    // ---- s3: a2 -> a3 (Cc[0:514)), d3 (Cc[514:1028)) ----
    for (int p = tid; p < 257; p += NT) {
        float2 u0 = *(const float2*)(A2 + 4*p - 2);
        float4 u1 = *(const float4*)(A2 + 4*p);
        float2 ap, dp;
        ap.x = lo0*u1.y + lo1*u1.x + lo2*u0.y + lo3*u0.x;
        dp.x = hi0*u1.y + hi1*u1.x + hi2*u0.y + hi3*u0.x;
        ap.y = lo0*u1.w + lo1*u1.z + lo2*u1.y + lo3*u1.x;
        dp.y = hi0*u1.w + hi1*u1.z + hi2*u1.y + hi3*u1.x;
        *(float2*)(Cc + 2*p)       = ap;
        *(float2*)(Cc + 514 + 2*p) = dp;
    }
    __syncthreads();

    // on-the-fly permuted-coefficient read: cp[i] = c[perm[i]] * g[i]
    auto CPj = [&](int j) -> float {     // raw permuted LDS read
        return Cc[j + (j >= 2054 ? 2 : 0)];
    };
    auto CP = [&](int i) -> float {
        return CPj(perm_idx[i]) * diag_g[i];
    };

    // ---- r1: cp[0:514) (a) + cp[2049:2563) (d) -> R1[0:1026) ----
    for (int k = tid; k < 513; k += NT) {
        float a0 = CP(k),        a1v = CP(k + 1);
        float d0 = CP(2049 + k), d1v = CP(2050 + k);
        float2 w;
        w.x = rl2*a0 + rl0*a1v + rh2*d0 + rh0*d1v;
        w.y = rl3*a0 + rl1*a1v + rh3*d0 + rh1*d1v;
        *(float2*)(R1 + 2*k) = w;
    }
    __syncthreads();

    // ---- r2+r3 fused: r2[4u..4u+4] in regs, then out quads * diag_s ----
    {
        const int u = tid;  // exactly 512 threads, 8 outputs each
        float2 q01 = *(const float2*)(R1 + 2*u);
        float2 q23 = *(const float2*)(R1 + 2*u + 2);
        // e = cp[1026+2u .. 1029+2u)  (even base -> aligned int2/float2 pairs)
        int2   pe0 = *(const int2*)(perm_idx + 1026 + 2*u);
        int2   pe1 = *(const int2*)(perm_idx + 1028 + 2*u);
        float2 ge0 = *(const float2*)(diag_g + 1026 + 2*u);
        float2 ge1 = *(const float2*)(diag_g + 1028 + 2*u);
        float e0 = CPj(pe0.x) * ge0.x, e1 = CPj(pe0.y) * ge0.y;
        float e2 = CPj(pe1.x) * ge1.x, e3 = CPj(pe1.y) * ge1.y;
        float s0  = rl2*q01.x + rl0*q01.y + rh2*e0 + rh0*e1;
        float s1v = rl3*q01.x + rl1*q01.y + rh3*e0 + rh1*e1;
        float s2v = rl2*q01.y + rl0*q23.x + rh2*e1 + rh0*e2;
        float s3v = rl3*q01.y + rl1*q23.x + rh3*e1 + rh1*e2;
        float s4  = rl2*q23.x + rl0*q23.y + rh2*e2 + rh0*e3;
        // f = cp[514+4u .. 518+4u]   (even base -> aligned pairs + scalar)
        int2   pf0 = *(const int2*)(perm_idx + 514 + 4*u);
        int2   pf1 = *(const int2*)(perm_idx + 516 + 4*u);
        int    pf2 = perm_idx[518 + 4*u];
        float2 gf0 = *(const float2*)(diag_g + 514 + 4*u);
        float2 gf1 = *(const float2*)(diag_g + 516 + 4*u);
        float  gf2 = diag_g[518 + 4*u];
        float f0 = CPj(pf0.x) * gf0.x, f1 = CPj(pf0.y) * gf0.y;
        float f2 = CPj(pf1.x) * gf1.x, f3 = CPj(pf1.y) * gf1.y;
        float f4 = CPj(pf2)   * gf2;
        float4 ss0 = ((const float4*)diag_s)[2*u];
        float4 ss1 = ((const float4*)diag_s)[2*u + 1];
        float4 o0, o1;
        o0.x = (rl2*s0  + rl0*s1v + rh2*f0 + rh0*f1) * ss0.x;
        o0.y = (rl3*s0  + rl1*s1v + rh3*f0 + rh1*f1) * ss0.y;
        o0.z = (rl2*s1v + rl0*s2v + rh2*f1 + rh0*f2) * ss0.z;
        o0.w = (rl3*s1v + rl1*s2v + rh3*f1 + rh1*f2) * ss0.w;
        o1.x = (rl2*s2v + rl0*s3v + rh2*f2 + rh0*f3) * ss1.x;
        o1.y = (rl3*s2v + rl1*s3v + rh3*f2 + rh1*f3) * ss1.y;
        o1.z = (rl2*s3v + rl0*s4  + rh2*f3 + rh0*f4) * ss1.z;
        o1.w = (rl3*s3v + rl1*s4  + rh3*f3 + rh1*f4) * ss1.w;
        float4* outr = (float4*)(out + row * 4096);
        outr[2*u]     = o0;
        outr[2*u + 1] = o1;
    }
}

extern "C" void kernel_launch(void* const* d_in, const int* in_sizes, int n_in,
                              void* d_out, int out_size, void* d_ws, size_t ws_size,
                              hipStream_t stream) {
    const float* x       = (const float*)d_in[0];
    const float* diag_b  = (const float*)d_in[1];
    const float* diag_g  = (const float*)d_in[2];
    const float* diag_s  = (const float*)d_in[3];
    const float* dec_lo  = (const float*)d_in[4];
    const float* dec_hi  = (const float*)d_in[5];
    const float* rec_lo  = (const float*)d_in[6];
    const float* rec_hi  = (const float*)d_in[7];
    const int*   perm    = (const int*)d_in[8];
    float* out = (float*)d_out;

    const int B = in_sizes[0] / 4096;  // 8192 rows
    wavelet_fused<<<B, NT, 0, stream>>>(
        x, diag_b, diag_g, diag_s, dec_lo, dec_hi, rec_lo, rec_hi, perm, out);
}

// Round 3
// 261.321 us; speedup vs baseline: 1.0313x; 1.0313x over previous
//
#include <hip/hip_runtime.h>

// WaveletLayer fused v3: materialized-but-truncated gather + register prefetch.
//  - s1 reads x*diag_b from global into registers (no a0 LDS staging).
//  - c materialized once in Cc (a3|d3|d2|gap2|d1).
//  - gather materializes ONLY the live prefix cp[0:2563) into rawA
//    (cp[2563:4103) is dead in the inverse). perm/diag_g/diag_s are
//    prefetched into registers at kernel start so their global-load
//    latency hides under s1-s3.
//  - r1 and fused r2+r3 read cp LINEARLY from LDS (conflict-free),
//    r2+r3 keeps everything in registers and writes out directly.
//  - 5 barriers. LDS = 28.8 KB -> 4 blocks/CU x 8 waves = 32 waves/CU.
//
// Cc layout: a3[0:514) d3[514:1028) d2[1028:2054) gap[2054:2056) d1@2056+[0:2049)
//            (gather translation: j >= 2054 ? j+2 : j)
// rawA: A1 = a1[-2..2052) @rawA+4, A2 = a2[-2..1028) @rawA+2060 (decomp);
//       then P = cp[0:2564) @rawA+0 (a1/a2 dead).
// R1 = r1[0:1026) @Cc+0 (c dead after gather).

#define NT 512

__global__ __launch_bounds__(NT, 8) void wavelet_fused(
    const float* __restrict__ x,
    const float* __restrict__ diag_b,
    const float* __restrict__ diag_g,
    const float* __restrict__ diag_s,
    const float* __restrict__ dec_lo,
    const float* __restrict__ dec_hi,
    const float* __restrict__ rec_lo,
    const float* __restrict__ rec_hi,
    const int*   __restrict__ perm_idx,
    float* __restrict__ out)
{
    __shared__ __align__(16) float rawA[3088];
    __shared__ __align__(16) float rawC[4112];
    float* const A1 = rawA + 4;     // a1[i], i in [-2, 2052)
    float* const A2 = rawA + 2060;  // a2[i], i in [-2, 1028)
    float* const P  = rawA;         // cp[0:2564) after decomposition
    float* const Cc = rawC;
    float* const R1 = rawC;         // r1[0:1026) after c is dead

    const int tid = threadIdx.x;
    const long row = blockIdx.x;

    // ---- prefetch row-invariant tables into registers (hides under s1-s3) ----
    int4   pq0 = ((const int4*)perm_idx)[tid];          // perm[4t .. 4t+4)
    float4 gq0 = ((const float4*)diag_g)[tid];
    int4   pq1; float4 gq1;
    if (tid < 128) {                                     // perm[2048 .. 2560)
        pq1 = ((const int4*)perm_idx)[512 + tid];
        gq1 = ((const float4*)diag_g)[512 + tid];
    }
    int pt = 0; float gt = 0.0f;
    if (tid < 3) { pt = perm_idx[2560 + tid]; gt = diag_g[2560 + tid]; }
    float4 sv0 = ((const float4*)diag_s)[2*tid];
    float4 sv1 = ((const float4*)diag_s)[2*tid + 1];

    const float lo0=dec_lo[0], lo1=dec_lo[1], lo2=dec_lo[2], lo3=dec_lo[3];
    const float hi0=dec_hi[0], hi1=dec_hi[1], hi2=dec_hi[2], hi3=dec_hi[3];
    const float rl0=rec_lo[0], rl1=rec_lo[1], rl2=rec_lo[2], rl3=rec_lo[3];
    const float rh0=rec_hi[0], rh1=rec_hi[1], rh2=rec_hi[2], rh3=rec_hi[3];

    // zero pads (a1[-2:0), a1[2049:2052), a2[-2:0), a2[1026:1028))
    if (tid < 2) rawA[2 + tid]    = 0.0f;
    if (tid < 3) rawA[2053 + tid] = 0.0f;
    if (tid < 2) rawA[2058 + tid] = 0.0f;
    if (tid < 2) rawA[3086 + tid] = 0.0f;

    // ---- s1: global regs -> a1 (A1), d1 (Cc d1 region) ----
    {
        const float* xr = x + row * 4096;
        float4 xv0 = *(const float4*)(xr + 8*tid);
        float4 xv1 = *(const float4*)(xr + 8*tid + 4);
        float4 bv0 = *(const float4*)(diag_b + 8*tid);
        float4 bv1 = *(const float4*)(diag_b + 8*tid + 4);
        float vm2 = 0.0f, vm1 = 0.0f;
        if (tid > 0) {
            float2 xm = *(const float2*)(xr + 8*tid - 2);
            float2 bm = *(const float2*)(diag_b + 8*tid - 2);
            vm2 = xm.x * bm.x; vm1 = xm.y * bm.y;
        }
        float v0 = xv0.x*bv0.x, v1 = xv0.y*bv0.y, v2 = xv0.z*bv0.z, v3 = xv0.w*bv0.w;
        float v4 = xv1.x*bv1.x, v5 = xv1.y*bv1.y, v6 = xv1.z*bv1.z, v7 = xv1.w*bv1.w;
        float4 av, dv;
        av.x = lo0*v1 + lo1*v0 + lo2*vm1 + lo3*vm2;
        dv.x = hi0*v1 + hi1*v0 + hi2*vm1 + hi3*vm2;
        av.y = lo0*v3 + lo1*v2 + lo2*v1 + lo3*v0;
        dv.y = hi0*v3 + hi1*v2 + hi2*v1 + hi3*v0;
        av.z = lo0*v5 + lo1*v4 + lo2*v3 + lo3*v2;
        dv.z = hi0*v5 + hi1*v4 + hi2*v3 + hi3*v2;
        av.w = lo0*v7 + lo1*v6 + lo2*v5 + lo3*v4;
        dv.w = hi0*v7 + hi1*v6 + hi2*v5 + hi3*v4;
        *(float4*)(A1 + 4*tid) = av;
        *(float4*)(Cc + 2056 + 4*tid) = dv;
        if (tid == 0) {
            // n = 2048 tail: x'[4096],x'[4097] = 0
            float xa = xr[4094]*diag_b[4094], xb = xr[4095]*diag_b[4095];
            A1[2048]        = lo2*xb + lo3*xa;
            Cc[2056 + 2048] = hi2*xb + hi3*xa;
        }
    }
    __syncthreads();

    // ---- s2: a1 -> a2 (A2), d2 -> Cc[1028+..] ----
    for (int p = tid; p < 513; p += NT) {
        float2 u0 = *(const float2*)(A1 + 4*p - 2);
        float4 u1 = *(const float4*)(A1 + 4*p);
        float2 ap, dp;
        ap.x = lo0*u1.y + lo1*u1.x + lo2*u0.y + lo3*u0.x;
        dp.x = hi0*u1.y + hi1*u1.x + hi2*u0.y + hi3*u0.x;
        ap.y = lo0*u1.w + lo1*u1.z + lo2*u1.y + lo3*u1.x;
        dp.y = hi0*u1.w + hi1*u1.z + hi2*u1.y + hi3*u1.x;
        *(float2*)(A2 + 2*p)        = ap;
        *(float2*)(Cc + 1028 + 2*p) = dp;
    }
    __syncthreads();

    // ---- s3: a2 -> a3 (Cc[0:514)), d3 (Cc[514:1028)) ----
    for (int p = tid; p < 257; p += NT) {
        float2 u0 = *(const float2*)(A2 + 4*p - 2);
        float4 u1 = *(const float4*)(A2 + 4*p);
        float2 ap, dp;
        ap.x = lo0*u1.y + lo1*u1.x + lo2*u0.y + lo3*u0.x;
        dp.x = hi0*u1.y + hi1*u1.x + hi2*u0.y + hi3*u0.x;
        ap.y = lo0*u1.w + lo1*u1.z + lo2*u1.y + lo3*u1.x;
        dp.y = hi0*u1.w + hi1*u1.z + hi2*u1.y + hi3*u1.x;
        *(float2*)(Cc + 2*p)       = ap;
        *(float2*)(Cc + 514 + 2*p) = dp;
    }
    __syncthreads();

    // ---- gather: cp[i] = c[perm[i]]*g[i] for i in [0:2563) only -> P ----
    {
        float4 cv;
        cv.x = Cc[pq0.x + (pq0.x >= 2054 ? 2 : 0)] * gq0.x;
        cv.y = Cc[pq0.y + (pq0.y >= 2054 ? 2 : 0)] * gq0.y;
        cv.z = Cc[pq0.z + (pq0.z >= 2054 ? 2 : 0)] * gq0.z;
        cv.w = Cc[pq0.w + (pq0.w >= 2054 ? 2 : 0)] * gq0.w;
        *(float4*)(P + 4*tid) = cv;                        // [0:2048)
        if (tid < 128) {
            float4 cw;
            cw.x = Cc[pq1.x + (pq1.x >= 2054 ? 2 : 0)] * gq1.x;
            cw.y = Cc[pq1.y + (pq1.y >= 2054 ? 2 : 0)] * gq1.y;
            cw.z = Cc[pq1.z + (pq1.z >= 2054 ? 2 : 0)] * gq1.z;
            cw.w = Cc[pq1.w + (pq1.w >= 2054 ? 2 : 0)] * gq1.w;
            *(float4*)(P + 2048 + 4*tid) = cw;             // [2048:2560)
        }
        if (tid < 3)  P[2560 + tid] = Cc[pt + (pt >= 2054 ? 2 : 0)] * gt;
        if (tid == 3) P[2563] = 0.0f;   // read (discarded) by r1 tail
    }
    __syncthreads();

    // ---- r1: a=cp[0:514), d=cp[2049:2563) -> R1[0:1026); linear LDS ----
    if (tid < 257) {
        int p0 = 2 * tid;
        float a0v = P[p0],        a1v = P[p0 + 1],    a2v = P[p0 + 2];
        float d0v = P[2049 + p0], d1v = P[2050 + p0], d2v = P[2051 + p0];
        float4 w;
        w.x = rl2*a0v + rl0*a1v + rh2*d0v + rh0*d1v;
        w.y = rl3*a0v + rl1*a1v + rh3*d0v + rh1*d1v;
        w.z = rl2*a1v + rl0*a2v + rh2*d1v + rh0*d2v;
        w.w = rl3*a1v + rl1*a2v + rh3*d1v + rh1*d2v;
        if (tid < 256) *(float4*)(R1 + 4*tid) = w;
        else           { R1[1024] = w.x; R1[1025] = w.y; }
    }
    __syncthreads();

    // ---- r2+r3 fused: r2[4u..4u+4] in regs, then out quads * diag_s ----
    {
        const int u = tid;
        float2 q01 = *(const float2*)(R1 + 2*u);
        float2 q23 = *(const float2*)(R1 + 2*u + 2);
        float2 ea  = *(const float2*)(P + 1026 + 2*u);     // cp[1026+2u..]
        float2 eb  = *(const float2*)(P + 1028 + 2*u);
        float e0 = ea.x, e1 = ea.y, e2 = eb.x, e3 = eb.y;
        float s0  = rl2*q01.x + rl0*q01.y + rh2*e0 + rh0*e1;
        float s1v = rl3*q01.x + rl1*q01.y + rh3*e0 + rh1*e1;
        float s2v = rl2*q01.y + rl0*q23.x + rh2*e1 + rh0*e2;
        float s3v = rl3*q01.y + rl1*q23.x + rh3*e1 + rh1*e2;
        float s4  = rl2*q23.x + rl0*q23.y + rh2*e2 + rh0*e3;
        float2 fa = *(const float2*)(P + 514 + 4*u);       // cp[514+4u..]
        float2 fb = *(const float2*)(P + 516 + 4*u);
        float  f4 = P[518 + 4*u];
        float f0 = fa.x, f1 = fa.y, f2 = fb.x, f3 = fb.y;
        float4 o0, o1;
        o0.x = (rl2*s0  + rl0*s1v + rh2*f0 + rh0*f1) * sv0.x;
        o0.y = (rl3*s0  + rl1*s1v + rh3*f0 + rh1*f1) * sv0.y;
        o0.z = (rl2*s1v + rl0*s2v + rh2*f1 + rh0*f2) * sv0.z;
        o0.w = (rl3*s1v + rl1*s2v + rh3*f1 + rh1*f2) * sv0.w;
        o1.x = (rl2*s2v + rl0*s3v + rh2*f2 + rh0*f3) * sv1.x;
        o1.y = (rl3*s2v + rl1*s3v + rh3*f2 + rh1*f3) * sv1.y;
        o1.z = (rl2*s3v + rl0*s4  + rh2*f3 + rh0*f4) * sv1.z;
        o1.w = (rl3*s3v + rl1*s4  + rh3*f3 + rh1*f4) * sv1.w;
        float4* outr = (float4*)(out + row * 4096);
        outr[2*u]     = o0;
        outr[2*u + 1] = o1;
    }
}

extern "C" void kernel_launch(void* const* d_in, const int* in_sizes, int n_in,
                              void* d_out, int out_size, void* d_ws, size_t ws_size,
                              hipStream_t stream) {
    const float* x       = (const float*)d_in[0];
    const float* diag_b  = (const float*)d_in[1];
    const float* diag_g  = (const float*)d_in[2];
    const float* diag_s  = (const float*)d_in[3];
    const float* dec_lo  = (const float*)d_in[4];
    const float* dec_hi  = (const float*)d_in[5];
    const float* rec_lo  = (const float*)d_in[6];
    const float* rec_hi  = (const float*)d_in[7];
    const int*   perm    = (const int*)d_in[8];
    float* out = (float*)d_out;

    const int B = in_sizes[0] / 4096;  // 8192 rows
    wavelet_fused<<<B, NT, 0, stream>>>(
        x, diag_b, diag_g, diag_s, dec_lo, dec_hi, rec_lo, rec_hi, perm, out);
}